// Round 17
// baseline (406.070 us; speedup 1.0000x reference)
//
#include <hip/hip_runtime.h>
#include <hip/hip_cooperative_groups.h>

namespace cg = cooperative_groups;

// CrossAttention on MI355X (gfx950), bf16 MFMA pipeline.
// Round 17: attn templated on NAT (16-row subtiles per block).
//   NAT=1: grid 512, 77KB LDS, 2 blocks/CU  (the occupancy lever)
//   NAT=2: grid 256, 154KB LDS, 1 block/CU  (round-15/16 proven fallback)
// Host tries coop 512/NAT=1 and FALLS BACK on launch error (round 4's silent
// failure came from an unchecked return code). wconv + prep verbatim r16.

typedef float f32x4 __attribute__((ext_vector_type(4)));
typedef short bf16x8 __attribute__((ext_vector_type(8)));
typedef unsigned u32x2 __attribute__((ext_vector_type(2)));

#define QSCALE 0.18033688011112042f   // 0.125 * log2(e); folded into Q so P = exp2(S)
#define PF 4                          // K-frags prefetched for next head

// f32 -> bf16 round-to-nearest-even (scalar path)
__device__ __forceinline__ short f2bf(float x) {
    union { float f; unsigned int u; } v;
    v.f = x;
    unsigned int r = v.u + 0x7FFFu + ((v.u >> 16) & 1u);
    return (short)(r >> 16);
}

// HW packed f32x2 -> bf16x2 (RNE), gfx950
__device__ __forceinline__ unsigned cvt_pk(float lo, float hi) {
    unsigned r;
    asm("v_cvt_pk_bf16_f32 %0, %1, %2" : "=v"(r) : "v"(lo), "v"(hi));
    return r;
}
__device__ __forceinline__ bf16x8 cvt8(float4 a0, float4 a1) {
    union { unsigned u[4]; bf16x8 v; } r;
    r.u[0] = cvt_pk(a0.x, a0.y);
    r.u[1] = cvt_pk(a0.z, a0.w);
    r.u[2] = cvt_pk(a1.x, a1.y);
    r.u[3] = cvt_pk(a1.z, a1.w);
    return r.v;
}

// D[16x16] = A[16x32] * B[32x16] + C.  A lane: row=l&15, k=(l>>4)*8+j.
// B lane: col=l&15, k=(l>>4)*8+j.  D lane: col=l&15, row=(l>>4)*4+reg.
__device__ __forceinline__ f32x4 mfma_bf16(bf16x8 a, bf16x8 b, f32x4 c) {
    return __builtin_amdgcn_mfma_f32_16x16x32_bf16(a, b, c, 0, 0, 0);
}

// ---------------------------------------------------------------------------
// Pass-1: convert all weight matrices to bf16 once (verbatim r16).
// ---------------------------------------------------------------------------
__global__ __launch_bounds__(256) void wconv_kernel(
    const float* __restrict__ wq, const float* __restrict__ wk,
    const float* __restrict__ wv, const float* __restrict__ wo,
    short* __restrict__ wqb, short* __restrict__ wkb,
    short* __restrict__ wvb, short* __restrict__ wof)
{
    const int z = blockIdx.y;
    const int t = blockIdx.x * 256 + threadIdx.x;   // 0..131071
    if (z == 0) {            // wq flat 1M elems
        const float* p = wq + (size_t)t * 8;
        *(bf16x8*)(wqb + (size_t)t * 8) =
            cvt8(*(const float4*)p, *(const float4*)(p + 4));
    } else if (z == 3) {     // wo -> B-frag
        const int col = t >> 7, k8 = t & 127;
        const float* p = wo + (size_t)col * 1024 + k8 * 8;
        *(bf16x8*)(wof + ((col >> 4) * 16384 + k8 * 128 + (col & 15) * 8)) =
            cvt8(*(const float4*)p, *(const float4*)(p + 4));
    } else {                 // wk / wv flat 768K elems
        if (t < 98304) {
            const float* src = (z == 1) ? wk : wv;
            short* dst = (z == 1) ? wkb : wvb;
            const float* p = src + (size_t)t * 8;
            *(bf16x8*)(dst + (size_t)t * 8) =
                cvt8(*(const float4*)p, *(const float4*)(p + 4));
        }
    }
}

// ---------------------------------------------------------------------------
// Projection GEMM body (verbatim r16: bf16 W, T14-lite prefetch, LDS epilogue)
// ---------------------------------------------------------------------------
template <int MODE>
__device__ __forceinline__ void proj_body(
    const float* __restrict__ Ain, const short* __restrict__ Wb,
    const float* __restrict__ bias, short* __restrict__ outb,
    short* sh)
{
    constexpr int KDIM = (MODE == 1 || MODE == 2) ? 768 : 1024;
    constexpr int NT = KDIM / 64;
    short* Alds = sh;
    short* Wlds = sh + 8192;

    const int tid  = threadIdx.x;
    const int lane = tid & 63;
    const int g = lane >> 4, c = lane & 15;
    const int wid = tid >> 6;
    const int wm = wid >> 1, wn = wid & 1;
    const int bn = blockIdx.y & 7;
    const int bm = blockIdx.x * 8 + (blockIdx.y >> 3);

    const int srow = tid >> 3;
    const int scol = (tid & 7) * 8;

    const float* Abase = Ain + (size_t)(bm * 128 + srow) * KDIM + scol;
    const short* Wbase = Wb + (size_t)(bn * 128 + srow) * KDIM + scol;

    f32x4 acc[4][4] = {};
    float4 Apre[2][2];
    bf16x8 Wpre[2];

    #pragma unroll
    for (int p = 0; p < 2; ++p) {
        const float* ap = Abase + (size_t)(p * 32) * KDIM;
        Apre[p][0] = *(const float4*)ap;
        Apre[p][1] = *(const float4*)(ap + 4);
        Wpre[p] = *(const bf16x8*)(Wbase + (size_t)(p * 32) * KDIM);
    }

    for (int kt = 0; kt < NT; ++kt) {
        const int k0 = kt * 64;
        __syncthreads();
        #pragma unroll
        for (int p = 0; p < 2; ++p) {
            const int r = p * 32 + srow;
            const int byt = (r * 128 + scol * 2) ^ ((r & 7) << 4);
            *(bf16x8*)((char*)Alds + byt) = cvt8(Apre[p][0], Apre[p][1]);
            *(bf16x8*)((char*)Wlds + byt) = Wpre[p];
        }
        if (kt + 1 < NT) {
            const int k0n = k0 + 64;
            #pragma unroll
            for (int p = 0; p < 2; ++p) {
                const float* ap = Abase + (size_t)(p * 32) * KDIM + k0n;
                Apre[p][0] = *(const float4*)ap;
                Apre[p][1] = *(const float4*)(ap + 4);
                Wpre[p] = *(const bf16x8*)(Wbase + (size_t)(p * 32) * KDIM + k0n);
            }
        }
        #pragma unroll
        for (int p = 2; p < 4; ++p) {
            const int r = p * 32 + srow;
            const float* ap = Abase + (size_t)(p * 32) * KDIM + k0;
            bf16x8 av = cvt8(*(const float4*)ap, *(const float4*)(ap + 4));
            bf16x8 wv8 = *(const bf16x8*)(Wbase + (size_t)(p * 32) * KDIM + k0);
            const int byt = (r * 128 + scol * 2) ^ ((r & 7) << 4);
            *(bf16x8*)((char*)Alds + byt) = av;
            *(bf16x8*)((char*)Wlds + byt) = wv8;
        }
        __syncthreads();
        #pragma unroll
        for (int kc = 0; kc < 2; ++kc) {
            bf16x8 af[4], bfr[4];
            #pragma unroll
            for (int t = 0; t < 4; ++t) {
                const int ra = wm * 64 + t * 16 + c;
                af[t]  = *(const bf16x8*)((const char*)Alds +
                          ((ra * 128 + (kc * 32 + g * 8) * 2) ^ ((ra & 7) << 4)));
                const int rb = wn * 64 + t * 16 + c;
                bfr[t] = *(const bf16x8*)((const char*)Wlds +
                          ((rb * 128 + (kc * 32 + g * 8) * 2) ^ ((rb & 7) << 4)));
            }
            #pragma unroll
            for (int i = 0; i < 4; ++i)
                #pragma unroll
                for (int j = 0; j < 4; ++j)
                    acc[i][j] = mfma_bf16(af[i], bfr[j], acc[i][j]);
        }
    }

    __syncthreads();
    #pragma unroll
    for (int j = 0; j < 4; ++j) {
        const int d = j * 16 + c;
        const float bv = bias[bn * 128 + wn * 64 + d];
        #pragma unroll
        for (int i = 0; i < 4; ++i) {
            #pragma unroll
            for (int r = 0; r < 4; ++r) {
                const int s = wm * 64 + i * 16 + g * 4 + r;
                float v = acc[i][j][r] + bv;
                if constexpr (MODE == 0) v *= QSCALE;
                int off;
                if constexpr (MODE == 0)
                    off = (s >> 4) * 1024 + (d >> 5) * 512 +
                          ((d >> 3) & 3) * 128 + (s & 15) * 8 + (d & 7);
                else if constexpr (MODE == 1)
                    off = (s >> 4) * 1024 + (d >> 3) * 128 + (s & 15) * 8 + (d & 7);
                else
                    off = (s >> 5) * 2048 + (d >> 4) * 512 +
                          ((s >> 3) & 3) * 128 + (d & 15) * 8 + (s & 7);
                sh[wn * 8192 + off] = f2bf(v);
            }
        }
    }
    __syncthreads();
    const int bglob = bm >> 3, bml = bm & 7;
    #pragma unroll
    for (int hl = 0; hl < 2; ++hl) {
        short* dst = outb + (size_t)(bglob * 16 + bn * 2 + hl) * 65536 + bml * 8192;
        #pragma unroll
        for (int k = 0; k < 4; ++k) {
            const int e = (k * 256 + tid) * 8;
            *(bf16x8*)(dst + e) = *(const bf16x8*)(sh + hl * 8192 + e);
        }
    }
}

__global__ __launch_bounds__(256, 4) void prep_kernel(
    const float* __restrict__ query, const float* __restrict__ key,
    const float* __restrict__ value,
    const short* __restrict__ wqb, const float* __restrict__ bq,
    const short* __restrict__ wkb, const float* __restrict__ bk,
    const short* __restrict__ wvb, const float* __restrict__ bv,
    short* __restrict__ qf, short* __restrict__ kf, short* __restrict__ vf)
{
    __shared__ short sh[16384];
    const int z = blockIdx.z;
    if (z == 0)      proj_body<0>(query, wqb, bq, qf, sh);
    else if (z == 1) proj_body<1>(key,   wkb, bk, kf, sh);
    else             proj_body<2>(value, wvb, bv, vf, sh);
}

// ---------------------------------------------------------------------------
// Cooperative attention + fused O-projection, templated on NAT (16-row
// subtiles per block).  Block = (b = bid&7, qt = bid>>3 covering NAT*16 rows),
// 512 threads (8 waves); wave w owns score cols [w*128,+128) for all rows.
// ONE barrier per head (parity-dbuf red + bf16 O slots).  grid = 8*(64/NAT).
// ---------------------------------------------------------------------------
template <int NAT>
__global__ __launch_bounds__(512, (NAT == 1 ? 4 : 2)) void attn_kernel(
    const short* Qf, const short* Kf, const short* Vf,
    const short* Wof, const float* bo, float* outp)
{
    __shared__ alignas(16) short Ohlds[NAT * 16 * 1024];     // 32/64KB
    __shared__ alignas(16) short pbufs[8 * NAT * 16 * 40];   // 10.25/20.5KB
    __shared__ alignas(16) short oaslb[2][8][NAT * 16][68];  // 34.8/68KB
    __shared__ alignas(16) float red[2][NAT][16][8];         // 1/2KB

    const int tid  = threadIdx.x;
    const int lane = tid & 63;
    const int w = tid >> 6;                  // 0..7
    const int g = lane >> 4, c = lane & 15;
    const int b = blockIdx.x & 7, qt = blockIdx.x >> 3;   // XCD-friendly split

    f32x4 am[NAT][8] = {};  // sum over heads of normalized P (attn.mean)

    bf16x8 qfr[NAT][2], kA[8];
    {
        const size_t hb0 = (size_t)(b * 16) * 65536;
        #pragma unroll
        for (int at = 0; at < NAT; ++at)
            #pragma unroll
            for (int kc = 0; kc < 2; ++kc)
                qfr[at][kc] = *(const bf16x8*)(Qf + hb0 +
                    (size_t)((qt * NAT + at) * 1024 + kc * 512 + g * 128 + c * 8));
        #pragma unroll
        for (int mt = 0; mt < PF; ++mt)
            kA[mt] = *(const bf16x8*)(Kf + hb0 +
                (size_t)((w * 8 + mt) * 1024 + g * 128 + c * 8));
    }

    for (int h = 0; h < 16; ++h) {
        const int par = h & 1;
        const size_t hb = (size_t)(b * 16 + h) * 65536;

        bf16x8 kB[8];
        #pragma unroll
        for (int mt = PF; mt < 8; ++mt)
            kA[mt] = *(const bf16x8*)(Kf + hb +
                (size_t)((w * 8 + mt) * 1024 + g * 128 + c * 8));
        #pragma unroll
        for (int mt = 0; mt < 8; ++mt)
            kB[mt] = *(const bf16x8*)(Kf + hb +
                (size_t)((w * 8 + mt) * 1024 + (4 + g) * 128 + c * 8));

        f32x4 p[NAT][8] = {};
        #pragma unroll
        for (int mt = 0; mt < 8; ++mt)
            #pragma unroll
            for (int at = 0; at < NAT; ++at)
                p[at][mt] = mfma_bf16(qfr[at][0], kA[mt], p[at][mt]);
        #pragma unroll
        for (int mt = 0; mt < 8; ++mt)
            #pragma unroll
            for (int at = 0; at < NAT; ++at)
                p[at][mt] = mfma_bf16(qfr[at][1], kB[mt], p[at][mt]);

        // exp2 (unclamped) + per-lane partial row sums
        f32x4 rs[NAT] = {};
        #pragma unroll
        for (int at = 0; at < NAT; ++at)
            #pragma unroll
            for (int mt = 0; mt < 8; ++mt) {
                f32x4 v = p[at][mt];
                #pragma unroll
                for (int r = 0; r < 4; ++r)
                    v[r] = __builtin_amdgcn_exp2f(v[r]);
                p[at][mt] = v;
                rs[at] += v;
            }
        #pragma unroll
        for (int off = 1; off < 16; off <<= 1)
            #pragma unroll
            for (int at = 0; at < NAT; ++at)
                #pragma unroll
                for (int r = 0; r < 4; ++r)
                    rs[at][r] += __shfl_xor(rs[at][r], off);
        if (c == 0) {
            #pragma unroll
            for (int at = 0; at < NAT; ++at)
                #pragma unroll
                for (int r = 0; r < 4; ++r)
                    red[par][at][g * 4 + r][w] = rs[at][r];
        }

        // PV on UNNORMALIZED P
        short* pbs = pbufs + w * (NAT * 16 * 40);
        f32x4 oa[NAT][4] = {};
        #pragma unroll
        for (int ks = 0; ks < 4; ++ks) {
            bf16x8 vfr[4];
            #pragma unroll
            for (int dt = 0; dt < 4; ++dt)
                vfr[dt] = *(const bf16x8*)(Vf + hb +
                    (size_t)(((w * 4 + ks) * 4 + dt) * 512 + g * 128 + c * 8));
            #pragma unroll
            for (int at = 0; at < NAT; ++at)
                #pragma unroll
                for (int m2 = 0; m2 < 2; ++m2)
                    #pragma unroll
                    for (int r = 0; r < 4; ++r)
                        pbs[(at * 16 + g * 4 + r) * 40 + m2 * 16 + c] =
                            f2bf(p[at][ks * 2 + m2][r]);
            asm volatile("s_waitcnt lgkmcnt(0)" ::: "memory");
            bf16x8 pa[NAT];
            #pragma unroll
            for (int at = 0; at < NAT; ++at)
                pa[at] = *(const bf16x8*)&pbs[(at * 16 + c) * 40 + g * 8];
            #pragma unroll
            for (int dt = 0; dt < 4; ++dt)
                #pragma unroll
                for (int at = 0; at < NAT; ++at)
                    oa[at][dt] = mfma_bf16(pa[at], vfr[dt], oa[at][dt]);
        }
        #pragma unroll
        for (int at = 0; at < NAT; ++at)
            #pragma unroll
            for (int dt = 0; dt < 4; ++dt)
                #pragma unroll
                for (int r = 0; r < 4; ++r)
                    oaslb[par][w][at * 16 + g * 4 + r][dt * 16 + c] =
                        f2bf(oa[at][dt][r]);

        // prefetch next head's Q frags + first PF K frags
        if (h < 15) {
            const size_t hbN = hb + 65536;
            #pragma unroll
            for (int at = 0; at < NAT; ++at)
                #pragma unroll
                for (int kc = 0; kc < 2; ++kc)
                    qfr[at][kc] = *(const bf16x8*)(Qf + hbN +
                        (size_t)((qt * NAT + at) * 1024 + kc * 512 + g * 128 + c * 8));
            #pragma unroll
            for (int mt = 0; mt < PF; ++mt)
                kA[mt] = *(const bf16x8*)(Kf + hbN +
                    (size_t)((w * 8 + mt) * 1024 + g * 128 + c * 8));
        }

        __syncthreads();   // the ONE barrier per head

        // per-lane rinv + attn-mean accumulation
        #pragma unroll
        for (int at = 0; at < NAT; ++at) {
            f32x4 rv;
            #pragma unroll
            for (int r = 0; r < 4; ++r) {
                f32x4 s0 = *(const f32x4*)&red[par][at][g * 4 + r][0];
                f32x4 s1 = *(const f32x4*)&red[par][at][g * 4 + r][4];
                f32x4 ss = s0 + s1;
                rv[r] = 1.0f / (ss[0] + ss[1] + ss[2] + ss[3]);
            }
            #pragma unroll
            for (int mt = 0; mt < 8; ++mt)
                am[at][mt] += p[at][mt] * rv;
        }

        // O tree-sum over 8 wave slots + normalize -> Ohlds
        {
            const int zn = tid >> 4, zd = (tid & 15) * 4;
            if (zn < NAT * 16) {
                const int zh = zn >> 4, zr = zn & 15;
                f32x4 s0 = *(const f32x4*)&red[par][zh][zr][0];
                f32x4 s1 = *(const f32x4*)&red[par][zh][zr][4];
                f32x4 ss = s0 + s1;
                const float inv = 1.0f / (ss[0] + ss[1] + ss[2] + ss[3]);
                f32x4 ov = {0.f, 0.f, 0.f, 0.f};
                #pragma unroll
                for (int i = 0; i < 8; ++i) {
                    u32x2 uu = *(const u32x2*)&oaslb[par][i][zn][zd];
                    union { unsigned u; float f; } e0, e1, e2, e3;
                    e0.u = uu[0] << 16;  e1.u = uu[0] & 0xFFFF0000u;
                    e2.u = uu[1] << 16;  e3.u = uu[1] & 0xFFFF0000u;
                    ov[0] += e0.f; ov[1] += e1.f; ov[2] += e2.f; ov[3] += e3.f;
                }
                u32x2 pk;
                pk[0] = cvt_pk(ov[0] * inv, ov[1] * inv);
                pk[1] = cvt_pk(ov[2] * inv, ov[3] * inv);
                unsigned byt = (unsigned)(zn * 2048 + (h * 64 + zd) * 2);
                byt ^= (unsigned)((zn & 7) << 4);
                *(u32x2*)((char*)Ohlds + byt) = pk;
            }
        }
        // no second barrier: next head's same-parity writes occur only after
        // the NEXT barrier, which every wave passes after its reads above.
    }

    __syncthreads();
    // ---- all blocks done reading qf/kf/vf hosted in d_out ----
    cg::this_grid().sync();

    // attn.mean(heads) -> out1 (clobbers qf/kf hosting)
    float* aout = outp + 8388608 + (size_t)b * 1048576;
    #pragma unroll
    for (int at = 0; at < NAT; ++at)
        #pragma unroll
        for (int mt = 0; mt < 8; ++mt)
            #pragma unroll
            for (int r = 0; r < 4; ++r) {
                const int n = qt * NAT * 16 + at * 16 + g * 4 + r;
                const int m = w * 128 + mt * 16 + c;
                aout[(size_t)n * 1024 + m] = am[at][mt][r] * 0.0625f;
            }

    // tail GEMM: out[NAT*16 rows][1024] = Ohlds @ w_o^T + b_o.
    f32x4 acc2[NAT][8] = {};
    for (int kt = 0; kt < 32; ++kt) {
        bf16x8 afr[NAT];
        #pragma unroll
        for (int at = 0; at < NAT; ++at) {
            const int row = at * 16 + c;
            unsigned byt = (unsigned)(row * 2048 + (kt * 32 + g * 8) * 2);
            byt ^= (unsigned)((row & 7) << 4);
            afr[at] = *(const bf16x8*)((const char*)Ohlds + byt);
        }
        #pragma unroll
        for (int ct = 0; ct < 8; ++ct) {
            bf16x8 bfr = *(const bf16x8*)(Wof +
                ((w * 8 + ct) * 16384 + (kt * 4 + g) * 128 + c * 8));
            #pragma unroll
            for (int at = 0; at < NAT; ++at)
                acc2[at][ct] = mfma_bf16(afr[at], bfr, acc2[at][ct]);
        }
    }
    #pragma unroll
    for (int ct = 0; ct < 8; ++ct) {
        const int col = w * 128 + ct * 16 + c;
        const float bv = bo[col];
        #pragma unroll
        for (int at = 0; at < NAT; ++at)
            #pragma unroll
            for (int r = 0; r < 4; ++r) {
                const int n = qt * NAT * 16 + at * 16 + g * 4 + r;
                outp[(size_t)(b * 1024 + n) * 1024 + col] = acc2[at][ct][r] + bv;
            }
    }
}

extern "C" void kernel_launch(void* const* d_in, const int* in_sizes, int n_in,
                              void* d_out, int out_size, void* d_ws, size_t ws_size,
                              hipStream_t stream)
{
    (void)in_sizes; (void)n_in; (void)out_size; (void)ws_size;
    const float* query = (const float*)d_in[0];
    const float* key   = (const float*)d_in[1];
    const float* value = (const float*)d_in[2];
    const float* w_q = (const float*)d_in[3];
    const float* b_q = (const float*)d_in[4];
    const float* w_k = (const float*)d_in[5];
    const float* b_k = (const float*)d_in[6];
    const float* w_v = (const float*)d_in[7];
    const float* b_v = (const float*)d_in[8];
    const float* w_o = (const float*)d_in[9];
    const float* b_o = (const float*)d_in[10];

    float* out = (float*)d_out;              // out0 [0,8M) floats; out1 [8M,16M)
    short* vf  = (short*)d_out;              // V frags hosted in out0 low (16.78MB)
    short* wqb = (short*)(out + 4194304);    // bf16 wq (2MB)  -- out0 upper half
    short* wkb = wqb + 1048576;              // bf16 wk (1.5MB)
    short* wvb = wkb + 786432;               // bf16 wv (1.5MB)
    short* qf  = (short*)(out + 8388608);    // Q frags hosted in out1 lower half
    short* kf  = qf + 8388608;               // K frags hosted in out1 upper half
    short* wof = (short*)d_ws;               // w_o bf16 frags (2MB — only ws use)

    wconv_kernel<<<dim3(512, 4), 256, 0, stream>>>(
        w_q, w_k, w_v, w_o, wqb, wkb, wvb, wof);

    prep_kernel<<<dim3(8, 64, 3), 256, 0, stream>>>(
        query, key, value, wqb, b_q, wkb, b_k, wvb, b_v, qf, kf, vf);

    void* args[] = { (void*)&qf, (void*)&kf, (void*)&vf,
                     (void*)&wof, (void*)&b_o, (void*)&out };
    hipError_t e = hipLaunchCooperativeKernel(attn_kernel<1>, dim3(512),
                                              dim3(512), args, 0u, stream);
    if (e != hipSuccess) {
        (void)hipGetLastError();   // clear sticky error, then proven fallback
        hipLaunchCooperativeKernel(attn_kernel<2>, dim3(256),
                                   dim3(512), args, 0u, stream);
    }
}

// Round 18
// 240.764 us; speedup vs baseline: 1.6866x; 1.6866x over previous
//
#include <hip/hip_runtime.h>
#include <hip/hip_cooperative_groups.h>

namespace cg = cooperative_groups;

// CrossAttention on MI355X (gfx950), bf16 MFMA pipeline.
// Round 18 = round 16 verbatim (best measured state, 240.6us).
// Round 17 closed the occupancy lever: NAT=1 @ 2 blocks/CU forces a 128-VGPR
// cap that the attn working set (~140 live regs) cannot meet -> spills
// (WRITE 352MB, attn 315us). 1 block/CU + zero spills is this structure's
// optimum. Pipeline: wconv (weights->bf16 once) -> prep (3 projections,
// XCD-partitioned, bf16 W, LDS epilogue) -> cooperative attn + fused O-proj.

typedef float f32x4 __attribute__((ext_vector_type(4)));
typedef short bf16x8 __attribute__((ext_vector_type(8)));
typedef unsigned u32x2 __attribute__((ext_vector_type(2)));

#define QSCALE 0.18033688011112042f   // 0.125 * log2(e); folded into Q so P = exp2(S)
#define PF 4                          // K-frags prefetched for next head

// f32 -> bf16 round-to-nearest-even (scalar path)
__device__ __forceinline__ short f2bf(float x) {
    union { float f; unsigned int u; } v;
    v.f = x;
    unsigned int r = v.u + 0x7FFFu + ((v.u >> 16) & 1u);
    return (short)(r >> 16);
}

// HW packed f32x2 -> bf16x2 (RNE), gfx950
__device__ __forceinline__ unsigned cvt_pk(float lo, float hi) {
    unsigned r;
    asm("v_cvt_pk_bf16_f32 %0, %1, %2" : "=v"(r) : "v"(lo), "v"(hi));
    return r;
}
__device__ __forceinline__ bf16x8 cvt8(float4 a0, float4 a1) {
    union { unsigned u[4]; bf16x8 v; } r;
    r.u[0] = cvt_pk(a0.x, a0.y);
    r.u[1] = cvt_pk(a0.z, a0.w);
    r.u[2] = cvt_pk(a1.x, a1.y);
    r.u[3] = cvt_pk(a1.z, a1.w);
    return r.v;
}

// D[16x16] = A[16x32] * B[32x16] + C.  A lane: row=l&15, k=(l>>4)*8+j.
// B lane: col=l&15, k=(l>>4)*8+j.  D lane: col=l&15, row=(l>>4)*4+reg.
__device__ __forceinline__ f32x4 mfma_bf16(bf16x8 a, bf16x8 b, f32x4 c) {
    return __builtin_amdgcn_mfma_f32_16x16x32_bf16(a, b, c, 0, 0, 0);
}

// ---------------------------------------------------------------------------
// Pass-1: convert all weight matrices to bf16 once.
// z=0: wq [1024][1024] -> bf16 row-major (out0 upper-half hosting)
// z=1: wk [1024][768]  -> bf16 row-major     "
// z=2: wv [1024][768]  -> bf16 row-major     "
// z=3: wo [1024][1024] -> bf16 B-frag layout (2MB ws)
// grid (512, 4) x 256 threads.
// ---------------------------------------------------------------------------
__global__ __launch_bounds__(256) void wconv_kernel(
    const float* __restrict__ wq, const float* __restrict__ wk,
    const float* __restrict__ wv, const float* __restrict__ wo,
    short* __restrict__ wqb, short* __restrict__ wkb,
    short* __restrict__ wvb, short* __restrict__ wof)
{
    const int z = blockIdx.y;
    const int t = blockIdx.x * 256 + threadIdx.x;   // 0..131071
    if (z == 0) {            // wq flat 1M elems
        const float* p = wq + (size_t)t * 8;
        *(bf16x8*)(wqb + (size_t)t * 8) =
            cvt8(*(const float4*)p, *(const float4*)(p + 4));
    } else if (z == 3) {     // wo -> B-frag: (col>>4)*16384 + k8*128 + (col&15)*8
        const int col = t >> 7, k8 = t & 127;
        const float* p = wo + (size_t)col * 1024 + k8 * 8;
        *(bf16x8*)(wof + ((col >> 4) * 16384 + k8 * 128 + (col & 15) * 8)) =
            cvt8(*(const float4*)p, *(const float4*)(p + 4));
    } else {                 // wk / wv flat 768K elems (guard)
        if (t < 98304) {
            const float* src = (z == 1) ? wk : wv;
            short* dst = (z == 1) ? wkb : wvb;
            const float* p = src + (size_t)t * 8;
            *(bf16x8*)(dst + (size_t)t * 8) =
                cvt8(*(const float4*)p, *(const float4*)(p + 4));
        }
    }
}

// ---------------------------------------------------------------------------
// Projection GEMM body: C[row,col] = sum_k A[row,k]*W[col,k] + bias[col]
// MODE 0: Q (KDIM=1024, *QSCALE, -> Q A-frag)   MODE 1: K (768, -> K B-frag)
// MODE 2: V (768, -> V B-frag, m-as-K)
// W is PRE-CONVERTED bf16 row-major: staging = single bf16x8 load -> ds_write.
// XCD-partitioned: bn = y&7, bm = x*8 + (y>>3).
// T14-lite: passes 0-1 of k-tile t+1 register-prefetched during compute of t.
// Epilogue: frag-layout staged in LDS, then coalesced dwordx4 stores.
// ---------------------------------------------------------------------------
template <int MODE>
__device__ __forceinline__ void proj_body(
    const float* __restrict__ Ain, const short* __restrict__ Wb,
    const float* __restrict__ bias, short* __restrict__ outb,
    short* sh)   // 16384 shorts: [0,8192)=Alds, [8192,16384)=Wlds during loop
{
    constexpr int KDIM = (MODE == 1 || MODE == 2) ? 768 : 1024;
    constexpr int NT = KDIM / 64;
    short* Alds = sh;
    short* Wlds = sh + 8192;

    const int tid  = threadIdx.x;
    const int lane = tid & 63;
    const int g = lane >> 4, c = lane & 15;
    const int wid = tid >> 6;
    const int wm = wid >> 1, wn = wid & 1;
    const int bn = blockIdx.y & 7;
    const int bm = blockIdx.x * 8 + (blockIdx.y >> 3);

    const int srow = tid >> 3;
    const int scol = (tid & 7) * 8;

    const float* Abase = Ain + (size_t)(bm * 128 + srow) * KDIM + scol;
    const short* Wbase = Wb + (size_t)(bn * 128 + srow) * KDIM + scol;

    f32x4 acc[4][4] = {};
    float4 Apre[2][2];     // prefetched A passes 0,1 (16 VGPRs)
    bf16x8 Wpre[2];        // prefetched W passes 0,1 (8 VGPRs)

    #pragma unroll
    for (int p = 0; p < 2; ++p) {
        const float* ap = Abase + (size_t)(p * 32) * KDIM;
        Apre[p][0] = *(const float4*)ap;
        Apre[p][1] = *(const float4*)(ap + 4);
        Wpre[p] = *(const bf16x8*)(Wbase + (size_t)(p * 32) * KDIM);
    }

    for (int kt = 0; kt < NT; ++kt) {
        const int k0 = kt * 64;
        __syncthreads();
        // passes 0,1 from prefetch registers
        #pragma unroll
        for (int p = 0; p < 2; ++p) {
            const int r = p * 32 + srow;
            const int byt = (r * 128 + scol * 2) ^ ((r & 7) << 4);
            *(bf16x8*)((char*)Alds + byt) = cvt8(Apre[p][0], Apre[p][1]);
            *(bf16x8*)((char*)Wlds + byt) = Wpre[p];
        }
        // prefetch next k-tile passes 0,1 (latency hides under compute below)
        if (kt + 1 < NT) {
            const int k0n = k0 + 64;
            #pragma unroll
            for (int p = 0; p < 2; ++p) {
                const float* ap = Abase + (size_t)(p * 32) * KDIM + k0n;
                Apre[p][0] = *(const float4*)ap;
                Apre[p][1] = *(const float4*)(ap + 4);
                Wpre[p] = *(const bf16x8*)(Wbase + (size_t)(p * 32) * KDIM + k0n);
            }
        }
        // passes 2,3 direct
        #pragma unroll
        for (int p = 2; p < 4; ++p) {
            const int r = p * 32 + srow;
            const float* ap = Abase + (size_t)(p * 32) * KDIM + k0;
            bf16x8 av = cvt8(*(const float4*)ap, *(const float4*)(ap + 4));
            bf16x8 wv8 = *(const bf16x8*)(Wbase + (size_t)(p * 32) * KDIM + k0);
            const int byt = (r * 128 + scol * 2) ^ ((r & 7) << 4);
            *(bf16x8*)((char*)Alds + byt) = av;
            *(bf16x8*)((char*)Wlds + byt) = wv8;
        }
        __syncthreads();
        #pragma unroll
        for (int kc = 0; kc < 2; ++kc) {
            bf16x8 af[4], bfr[4];
            #pragma unroll
            for (int t = 0; t < 4; ++t) {
                const int ra = wm * 64 + t * 16 + c;
                af[t]  = *(const bf16x8*)((const char*)Alds +
                          ((ra * 128 + (kc * 32 + g * 8) * 2) ^ ((ra & 7) << 4)));
                const int rb = wn * 64 + t * 16 + c;
                bfr[t] = *(const bf16x8*)((const char*)Wlds +
                          ((rb * 128 + (kc * 32 + g * 8) * 2) ^ ((rb & 7) << 4)));
            }
            #pragma unroll
            for (int i = 0; i < 4; ++i)
                #pragma unroll
                for (int j = 0; j < 4; ++j)
                    acc[i][j] = mfma_bf16(af[i], bfr[j], acc[i][j]);
        }
    }

    // ---- epilogue: stage frag layout in LDS, then coalesced global stores ----
    __syncthreads();   // tile buffers dead; safe to overwrite
    #pragma unroll
    for (int j = 0; j < 4; ++j) {
        const int d = j * 16 + c;                       // 0..63 within head
        const float bv = bias[bn * 128 + wn * 64 + d];
        #pragma unroll
        for (int i = 0; i < 4; ++i) {
            #pragma unroll
            for (int r = 0; r < 4; ++r) {
                const int s = wm * 64 + i * 16 + g * 4 + r;   // 0..127 local row
                float v = acc[i][j][r] + bv;
                if constexpr (MODE == 0) v *= QSCALE;
                int off;
                if constexpr (MODE == 0)       // A-frag
                    off = (s >> 4) * 1024 + (d >> 5) * 512 +
                          ((d >> 3) & 3) * 128 + (s & 15) * 8 + (d & 7);
                else if constexpr (MODE == 1)  // K B-frag
                    off = (s >> 4) * 1024 + (d >> 3) * 128 + (s & 15) * 8 + (d & 7);
                else                           // V B-frag (k = m)
                    off = (s >> 5) * 2048 + (d >> 4) * 512 +
                          ((s >> 3) & 3) * 128 + (d & 15) * 8 + (s & 7);
                sh[wn * 8192 + off] = f2bf(v);
            }
        }
    }
    __syncthreads();
    // two contiguous 8192-short chunks (heads bn*2, bn*2+1), coalesced copy
    const int bglob = bm >> 3, bml = bm & 7;
    #pragma unroll
    for (int hl = 0; hl < 2; ++hl) {
        short* dst = outb + (size_t)(bglob * 16 + bn * 2 + hl) * 65536 + bml * 8192;
        #pragma unroll
        for (int k = 0; k < 4; ++k) {
            const int e = (k * 256 + tid) * 8;          // 16B-granule offset
            *(bf16x8*)(dst + e) = *(const bf16x8*)(sh + hl * 8192 + e);
        }
    }
}

// ---------------------------------------------------------------------------
// Fused prologue: z=0 Q proj, z=1 K proj, z=2 V proj (W pre-converted bf16).
// grid (8, 64, 3) x 256 threads, 4 blocks/CU (proven no-spill regime).
// ---------------------------------------------------------------------------
__global__ __launch_bounds__(256, 4) void prep_kernel(
    const float* __restrict__ query, const float* __restrict__ key,
    const float* __restrict__ value,
    const short* __restrict__ wqb, const float* __restrict__ bq,
    const short* __restrict__ wkb, const float* __restrict__ bk,
    const short* __restrict__ wvb, const float* __restrict__ bv,
    short* __restrict__ qf, short* __restrict__ kf, short* __restrict__ vf)
{
    __shared__ short sh[16384];   // 32KB: A/W tiles during loop, frag stage after
    const int z = blockIdx.z;
    if (z == 0)      proj_body<0>(query, wqb, bq, qf, sh);
    else if (z == 1) proj_body<1>(key,   wkb, bk, kf, sh);
    else             proj_body<2>(value, wvb, bv, vf, sh);
}

// ---------------------------------------------------------------------------
// Cooperative attention + fused O-projection.
// ONE barrier per head: red + O-slots parity-double-buffered by h&1
// (O slots bf16 so the parity copy fits LDS). 1 block/CU, zero spills.
// Block = (batch b = bid&7, 32-row q-tile qt = bid>>3), 512 threads (8 waves),
// grid 256.  Wave w owns score cols [w*128,+128), all 32 rows.
// ---------------------------------------------------------------------------
__global__ __launch_bounds__(512, 2) void attn_kernel(
    const short* Qf, const short* Kf, const short* Vf,
    const short* Wof, const float* bo, float* outp)
{
    __shared__ alignas(16) short Ohlds[32 * 1024];      // 64KB attn out, swizzled
    __shared__ alignas(16) short pbufs[8 * 32 * 40];    // 20.5KB bf16 P bounce
    __shared__ alignas(16) short oaslb[2][8][32][72];   // 72KB bf16 O slots (dbuf)
    __shared__ alignas(16) float red[2][2][16][8];      // 2KB row-sum partials (dbuf)

    const int tid  = threadIdx.x;
    const int lane = tid & 63;
    const int w = tid >> 6;                  // 0..7
    const int g = lane >> 4, c = lane & 15;
    const int b = blockIdx.x & 7, qt = blockIdx.x >> 3;   // XCD-friendly split

    f32x4 am[2][8] = {};  // sum over heads of normalized P (attn.mean)

    // prologue: head-0 Q frags + first PF K frags (kc=0)
    bf16x8 qfr[2][2], kA[8];
    {
        const size_t hb0 = (size_t)(b * 16) * 65536;
        #pragma unroll
        for (int at = 0; at < 2; ++at)
            #pragma unroll
            for (int kc = 0; kc < 2; ++kc)
                qfr[at][kc] = *(const bf16x8*)(Qf + hb0 +
                    (size_t)((qt * 2 + at) * 1024 + kc * 512 + g * 128 + c * 8));
        #pragma unroll
        for (int mt = 0; mt < PF; ++mt)
            kA[mt] = *(const bf16x8*)(Kf + hb0 +
                (size_t)((w * 8 + mt) * 1024 + g * 128 + c * 8));
    }

    for (int h = 0; h < 16; ++h) {
        const int par = h & 1;
        const size_t hb = (size_t)(b * 16 + h) * 65536;

        // finish K loads for this head (batched issue, then MFMAs)
        bf16x8 kB[8];
        #pragma unroll
        for (int mt = PF; mt < 8; ++mt)
            kA[mt] = *(const bf16x8*)(Kf + hb +
                (size_t)((w * 8 + mt) * 1024 + g * 128 + c * 8));
        #pragma unroll
        for (int mt = 0; mt < 8; ++mt)
            kB[mt] = *(const bf16x8*)(Kf + hb +
                (size_t)((w * 8 + mt) * 1024 + (4 + g) * 128 + c * 8));

        f32x4 p[2][8] = {};
        #pragma unroll
        for (int mt = 0; mt < 8; ++mt) {
            p[0][mt] = mfma_bf16(qfr[0][0], kA[mt], p[0][mt]);
            p[1][mt] = mfma_bf16(qfr[1][0], kA[mt], p[1][mt]);
        }
        #pragma unroll
        for (int mt = 0; mt < 8; ++mt) {
            p[0][mt] = mfma_bf16(qfr[0][1], kB[mt], p[0][mt]);
            p[1][mt] = mfma_bf16(qfr[1][1], kB[mt], p[1][mt]);
        }

        // exp2 (unclamped: scores sigma~0.5, overflow impossible) + row sums
        f32x4 rs[2] = {};
        #pragma unroll
        for (int at = 0; at < 2; ++at)
            #pragma unroll
            for (int mt = 0; mt < 8; ++mt) {
                f32x4 v = p[at][mt];
                #pragma unroll
                for (int r = 0; r < 4; ++r)
                    v[r] = __builtin_amdgcn_exp2f(v[r]);
                p[at][mt] = v;
                rs[at] += v;
            }
        #pragma unroll
        for (int off = 1; off < 16; off <<= 1)
            #pragma unroll
            for (int at = 0; at < 2; ++at)
                #pragma unroll
                for (int r = 0; r < 4; ++r)
                    rs[at][r] += __shfl_xor(rs[at][r], off);
        if (c == 0) {
            #pragma unroll
            for (int at = 0; at < 2; ++at)
                #pragma unroll
                for (int r = 0; r < 4; ++r)
                    red[par][at][g * 4 + r][w] = rs[at][r];
        }

        // PV on UNNORMALIZED P: V loads hoisted above the bf16 bounce
        short* pbs = pbufs + w * 1280;
        f32x4 oa[2][4] = {};
        #pragma unroll
        for (int ks = 0; ks < 4; ++ks) {
            bf16x8 vfr[4];
            #pragma unroll
            for (int dt = 0; dt < 4; ++dt)
                vfr[dt] = *(const bf16x8*)(Vf + hb +
                    (size_t)(((w * 4 + ks) * 4 + dt) * 512 + g * 128 + c * 8));
            #pragma unroll
            for (int at = 0; at < 2; ++at)
                #pragma unroll
                for (int m2 = 0; m2 < 2; ++m2)
                    #pragma unroll
                    for (int r = 0; r < 4; ++r)
                        pbs[(at * 16 + g * 4 + r) * 40 + m2 * 16 + c] =
                            f2bf(p[at][ks * 2 + m2][r]);
            asm volatile("s_waitcnt lgkmcnt(0)" ::: "memory");
            bf16x8 pa[2];
            #pragma unroll
            for (int at = 0; at < 2; ++at)
                pa[at] = *(const bf16x8*)&pbs[(at * 16 + c) * 40 + g * 8];
            #pragma unroll
            for (int dt = 0; dt < 4; ++dt) {
                oa[0][dt] = mfma_bf16(pa[0], vfr[dt], oa[0][dt]);
                oa[1][dt] = mfma_bf16(pa[1], vfr[dt], oa[1][dt]);
            }
        }
        // per-wave O slot (bf16, parity-buffered; plain stores, no atomics)
        #pragma unroll
        for (int at = 0; at < 2; ++at)
            #pragma unroll
            for (int dt = 0; dt < 4; ++dt)
                #pragma unroll
                for (int r = 0; r < 4; ++r)
                    oaslb[par][w][at * 16 + g * 4 + r][dt * 16 + c] =
                        f2bf(oa[at][dt][r]);

        // prefetch next head's Q frags + first PF K frags (hide under barrier)
        if (h < 15) {
            const size_t hbN = hb + 65536;
            #pragma unroll
            for (int at = 0; at < 2; ++at)
                #pragma unroll
                for (int kc = 0; kc < 2; ++kc)
                    qfr[at][kc] = *(const bf16x8*)(Qf + hbN +
                        (size_t)((qt * 2 + at) * 1024 + kc * 512 + g * 128 + c * 8));
            #pragma unroll
            for (int mt = 0; mt < PF; ++mt)
                kA[mt] = *(const bf16x8*)(Kf + hbN +
                    (size_t)((w * 8 + mt) * 1024 + g * 128 + c * 8));
        }

        __syncthreads();   // the ONE barrier per head: red + oaslb visible

        // per-lane rinv + attn-mean accumulation (p still in registers)
        #pragma unroll
        for (int at = 0; at < 2; ++at) {
            f32x4 rv;
            #pragma unroll
            for (int r = 0; r < 4; ++r) {
                f32x4 s0 = *(const f32x4*)&red[par][at][g * 4 + r][0];
                f32x4 s1 = *(const f32x4*)&red[par][at][g * 4 + r][4];
                f32x4 ss = s0 + s1;
                rv[r] = 1.0f / (ss[0] + ss[1] + ss[2] + ss[3]);
            }
            #pragma unroll
            for (int mt = 0; mt < 8; ++mt)
                am[at][mt] += p[at][mt] * rv;
        }

        // O tree-sum over 8 wave slots (bf16 unpack) + normalize -> Ohlds
        {
            const int zn = tid >> 4, zd = (tid & 15) * 4;   // zn 0..31
            const int zh = zn >> 4, zr = zn & 15;
            f32x4 s0 = *(const f32x4*)&red[par][zh][zr][0];
            f32x4 s1 = *(const f32x4*)&red[par][zh][zr][4];
            f32x4 ss = s0 + s1;
            const float inv = 1.0f / (ss[0] + ss[1] + ss[2] + ss[3]);
            f32x4 ov = {0.f, 0.f, 0.f, 0.f};
            #pragma unroll
            for (int i = 0; i < 8; ++i) {
                u32x2 uu = *(const u32x2*)&oaslb[par][i][zn][zd];
                union { unsigned u; float f; } e0, e1, e2, e3;
                e0.u = uu[0] << 16;  e1.u = uu[0] & 0xFFFF0000u;
                e2.u = uu[1] << 16;  e3.u = uu[1] & 0xFFFF0000u;
                ov[0] += e0.f; ov[1] += e1.f; ov[2] += e2.f; ov[3] += e3.f;
            }
            u32x2 pk;
            pk[0] = cvt_pk(ov[0] * inv, ov[1] * inv);
            pk[1] = cvt_pk(ov[2] * inv, ov[3] * inv);
            unsigned byt = (unsigned)(zn * 2048 + (h * 64 + zd) * 2);
            byt ^= (unsigned)((zn & 7) << 4);          // XOR swizzle
            *(u32x2*)((char*)Ohlds + byt) = pk;
        }
        // no second barrier: next head's same-parity writes occur only after
        // the NEXT barrier, which every wave passes after its reads above.
    }

    __syncthreads();
    // ---- all blocks done reading qf/kf/vf hosted in d_out ----
    cg::this_grid().sync();

    // attn.mean(heads) -> out1 (clobbers qf/kf hosting; frees am)
    float* aout = outp + 8388608 + (size_t)b * 1048576;
    #pragma unroll
    for (int at = 0; at < 2; ++at)
        #pragma unroll
        for (int mt = 0; mt < 8; ++mt)
            #pragma unroll
            for (int r = 0; r < 4; ++r) {
                const int n = qt * 32 + at * 16 + g * 4 + r;
                const int m = w * 128 + mt * 16 + c;
                aout[(size_t)n * 1024 + m] = am[at][mt][r] * 0.0625f;
            }

    // tail GEMM: out[32 rows][1024] = Ohlds(32x1024) @ w_o^T + b_o.
    // wave w: cols w*128..+128, both 16-row subtiles (clobbers vf hosting).
    f32x4 acc2[2][8] = {};
    for (int kt = 0; kt < 32; ++kt) {
        bf16x8 afr[2];
        #pragma unroll
        for (int at = 0; at < 2; ++at) {
            const int row = at * 16 + c;
            unsigned byt = (unsigned)(row * 2048 + (kt * 32 + g * 8) * 2);
            byt ^= (unsigned)((row & 7) << 4);
            afr[at] = *(const bf16x8*)((const char*)Ohlds + byt);
        }
        #pragma unroll
        for (int ct = 0; ct < 8; ++ct) {
            bf16x8 bfr = *(const bf16x8*)(Wof +
                ((w * 8 + ct) * 16384 + (kt * 4 + g) * 128 + c * 8));
            acc2[0][ct] = mfma_bf16(afr[0], bfr, acc2[0][ct]);
            acc2[1][ct] = mfma_bf16(afr[1], bfr, acc2[1][ct]);
        }
    }
    #pragma unroll
    for (int ct = 0; ct < 8; ++ct) {
        const int col = w * 128 + ct * 16 + c;
        const float bv = bo[col];
        #pragma unroll
        for (int at = 0; at < 2; ++at)
            #pragma unroll
            for (int r = 0; r < 4; ++r) {
                const int n = qt * 32 + at * 16 + g * 4 + r;
                outp[(size_t)(b * 1024 + n) * 1024 + col] = acc2[at][ct][r] + bv;
            }
    }
}

extern "C" void kernel_launch(void* const* d_in, const int* in_sizes, int n_in,
                              void* d_out, int out_size, void* d_ws, size_t ws_size,
                              hipStream_t stream)
{
    (void)in_sizes; (void)n_in; (void)out_size; (void)ws_size;
    const float* query = (const float*)d_in[0];
    const float* key   = (const float*)d_in[1];
    const float* value = (const float*)d_in[2];
    const float* w_q = (const float*)d_in[3];
    const float* b_q = (const float*)d_in[4];
    const float* w_k = (const float*)d_in[5];
    const float* b_k = (const float*)d_in[6];
    const float* w_v = (const float*)d_in[7];
    const float* b_v = (const float*)d_in[8];
    const float* w_o = (const float*)d_in[9];
    const float* b_o = (const float*)d_in[10];

    float* out = (float*)d_out;              // out0 [0,8M) floats; out1 [8M,16M)
    short* vf  = (short*)d_out;              // V frags hosted in out0 low (16.78MB)
    short* wqb = (short*)(out + 4194304);    // bf16 wq (2MB)  -- out0 upper half,
    short* wkb = wqb + 1048576;              // bf16 wk (1.5MB)   written pass-1,
    short* wvb = wkb + 786432;               // bf16 wv (1.5MB)   read by prep,
                                             //   clobbered only by attn's final
                                             //   out0 write (after grid.sync)
    short* qf  = (short*)(out + 8388608);    // Q frags hosted in out1 lower half
    short* kf  = qf + 8388608;               // K frags hosted in out1 upper half
    short* wof = (short*)d_ws;               // w_o bf16 frags (2MB — only ws use)

    wconv_kernel<<<dim3(512, 4), 256, 0, stream>>>(
        w_q, w_k, w_v, w_o, wqb, wkb, wvb, wof);

    prep_kernel<<<dim3(8, 64, 3), 256, 0, stream>>>(
        query, key, value, wqb, b_q, wkb, b_k, wvb, b_v, qf, kf, vf);

    void* args[] = { (void*)&qf, (void*)&kf, (void*)&vf,
                     (void*)&wof, (void*)&b_o, (void*)&out };
    hipLaunchCooperativeKernel(attn_kernel, dim3(256), dim3(512), args, 0u, stream);
}

// Round 19
// 240.471 us; speedup vs baseline: 1.6886x; 1.0012x over previous
//
#include <hip/hip_runtime.h>
#include <hip/hip_cooperative_groups.h>

namespace cg = cooperative_groups;

// CrossAttention on MI355X (gfx950), bf16 MFMA pipeline.
// Round 19: the r8/r13/r17 spills all show VGPR_Count pinned at 128 -- the
// allocator targets a 4-wave/SIMD boundary that LDS (1 block/CU, 2 waves/SIMD)
// makes irrelevant, and spills rather than exceed it. attn<DEEP=1> lifts the
// cap with __launch_bounds__(512,1) and reinstates round-13's V-2x8 batching
// (batch 1 hidden under softmax). attn<0> = round-16 verbatim fallback chosen
// via a host-side occupancy query (graph-safe, deterministic).

typedef float f32x4 __attribute__((ext_vector_type(4)));
typedef short bf16x8 __attribute__((ext_vector_type(8)));
typedef unsigned u32x2 __attribute__((ext_vector_type(2)));

#define QSCALE 0.18033688011112042f   // 0.125 * log2(e); folded into Q so P = exp2(S)
#define PF 4                          // K-frags prefetched for next head

// f32 -> bf16 round-to-nearest-even (scalar path)
__device__ __forceinline__ short f2bf(float x) {
    union { float f; unsigned int u; } v;
    v.f = x;
    unsigned int r = v.u + 0x7FFFu + ((v.u >> 16) & 1u);
    return (short)(r >> 16);
}

// HW packed f32x2 -> bf16x2 (RNE), gfx950
__device__ __forceinline__ unsigned cvt_pk(float lo, float hi) {
    unsigned r;
    asm("v_cvt_pk_bf16_f32 %0, %1, %2" : "=v"(r) : "v"(lo), "v"(hi));
    return r;
}
__device__ __forceinline__ bf16x8 cvt8(float4 a0, float4 a1) {
    union { unsigned u[4]; bf16x8 v; } r;
    r.u[0] = cvt_pk(a0.x, a0.y);
    r.u[1] = cvt_pk(a0.z, a0.w);
    r.u[2] = cvt_pk(a1.x, a1.y);
    r.u[3] = cvt_pk(a1.z, a1.w);
    return r.v;
}

// D[16x16] = A[16x32] * B[32x16] + C.
__device__ __forceinline__ f32x4 mfma_bf16(bf16x8 a, bf16x8 b, f32x4 c) {
    return __builtin_amdgcn_mfma_f32_16x16x32_bf16(a, b, c, 0, 0, 0);
}

// ---------------------------------------------------------------------------
// Pass-1: convert all weight matrices to bf16 once (verbatim r16).
// ---------------------------------------------------------------------------
__global__ __launch_bounds__(256) void wconv_kernel(
    const float* __restrict__ wq, const float* __restrict__ wk,
    const float* __restrict__ wv, const float* __restrict__ wo,
    short* __restrict__ wqb, short* __restrict__ wkb,
    short* __restrict__ wvb, short* __restrict__ wof)
{
    const int z = blockIdx.y;
    const int t = blockIdx.x * 256 + threadIdx.x;   // 0..131071
    if (z == 0) {
        const float* p = wq + (size_t)t * 8;
        *(bf16x8*)(wqb + (size_t)t * 8) =
            cvt8(*(const float4*)p, *(const float4*)(p + 4));
    } else if (z == 3) {
        const int col = t >> 7, k8 = t & 127;
        const float* p = wo + (size_t)col * 1024 + k8 * 8;
        *(bf16x8*)(wof + ((col >> 4) * 16384 + k8 * 128 + (col & 15) * 8)) =
            cvt8(*(const float4*)p, *(const float4*)(p + 4));
    } else {
        if (t < 98304) {
            const float* src = (z == 1) ? wk : wv;
            short* dst = (z == 1) ? wkb : wvb;
            const float* p = src + (size_t)t * 8;
            *(bf16x8*)(dst + (size_t)t * 8) =
                cvt8(*(const float4*)p, *(const float4*)(p + 4));
        }
    }
}

// ---------------------------------------------------------------------------
// Projection GEMM body (verbatim r16: bf16 W, T14-lite prefetch, LDS epilogue)
// ---------------------------------------------------------------------------
template <int MODE>
__device__ __forceinline__ void proj_body(
    const float* __restrict__ Ain, const short* __restrict__ Wb,
    const float* __restrict__ bias, short* __restrict__ outb,
    short* sh)
{
    constexpr int KDIM = (MODE == 1 || MODE == 2) ? 768 : 1024;
    constexpr int NT = KDIM / 64;
    short* Alds = sh;
    short* Wlds = sh + 8192;

    const int tid  = threadIdx.x;
    const int lane = tid & 63;
    const int g = lane >> 4, c = lane & 15;
    const int wid = tid >> 6;
    const int wm = wid >> 1, wn = wid & 1;
    const int bn = blockIdx.y & 7;
    const int bm = blockIdx.x * 8 + (blockIdx.y >> 3);

    const int srow = tid >> 3;
    const int scol = (tid & 7) * 8;

    const float* Abase = Ain + (size_t)(bm * 128 + srow) * KDIM + scol;
    const short* Wbase = Wb + (size_t)(bn * 128 + srow) * KDIM + scol;

    f32x4 acc[4][4] = {};
    float4 Apre[2][2];
    bf16x8 Wpre[2];

    #pragma unroll
    for (int p = 0; p < 2; ++p) {
        const float* ap = Abase + (size_t)(p * 32) * KDIM;
        Apre[p][0] = *(const float4*)ap;
        Apre[p][1] = *(const float4*)(ap + 4);
        Wpre[p] = *(const bf16x8*)(Wbase + (size_t)(p * 32) * KDIM);
    }

    for (int kt = 0; kt < NT; ++kt) {
        const int k0 = kt * 64;
        __syncthreads();
        #pragma unroll
        for (int p = 0; p < 2; ++p) {
            const int r = p * 32 + srow;
            const int byt = (r * 128 + scol * 2) ^ ((r & 7) << 4);
            *(bf16x8*)((char*)Alds + byt) = cvt8(Apre[p][0], Apre[p][1]);
            *(bf16x8*)((char*)Wlds + byt) = Wpre[p];
        }
        if (kt + 1 < NT) {
            const int k0n = k0 + 64;
            #pragma unroll
            for (int p = 0; p < 2; ++p) {
                const float* ap = Abase + (size_t)(p * 32) * KDIM + k0n;
                Apre[p][0] = *(const float4*)ap;
                Apre[p][1] = *(const float4*)(ap + 4);
                Wpre[p] = *(const bf16x8*)(Wbase + (size_t)(p * 32) * KDIM + k0n);
            }
        }
        #pragma unroll
        for (int p = 2; p < 4; ++p) {
            const int r = p * 32 + srow;
            const float* ap = Abase + (size_t)(p * 32) * KDIM + k0;
            bf16x8 av = cvt8(*(const float4*)ap, *(const float4*)(ap + 4));
            bf16x8 wv8 = *(const bf16x8*)(Wbase + (size_t)(p * 32) * KDIM + k0);
            const int byt = (r * 128 + scol * 2) ^ ((r & 7) << 4);
            *(bf16x8*)((char*)Alds + byt) = av;
            *(bf16x8*)((char*)Wlds + byt) = wv8;
        }
        __syncthreads();
        #pragma unroll
        for (int kc = 0; kc < 2; ++kc) {
            bf16x8 af[4], bfr[4];
            #pragma unroll
            for (int t = 0; t < 4; ++t) {
                const int ra = wm * 64 + t * 16 + c;
                af[t]  = *(const bf16x8*)((const char*)Alds +
                          ((ra * 128 + (kc * 32 + g * 8) * 2) ^ ((ra & 7) << 4)));
                const int rb = wn * 64 + t * 16 + c;
                bfr[t] = *(const bf16x8*)((const char*)Wlds +
                          ((rb * 128 + (kc * 32 + g * 8) * 2) ^ ((rb & 7) << 4)));
            }
            #pragma unroll
            for (int i = 0; i < 4; ++i)
                #pragma unroll
                for (int j = 0; j < 4; ++j)
                    acc[i][j] = mfma_bf16(af[i], bfr[j], acc[i][j]);
        }
    }

    __syncthreads();
    #pragma unroll
    for (int j = 0; j < 4; ++j) {
        const int d = j * 16 + c;
        const float bv = bias[bn * 128 + wn * 64 + d];
        #pragma unroll
        for (int i = 0; i < 4; ++i) {
            #pragma unroll
            for (int r = 0; r < 4; ++r) {
                const int s = wm * 64 + i * 16 + g * 4 + r;
                float v = acc[i][j][r] + bv;
                if constexpr (MODE == 0) v *= QSCALE;
                int off;
                if constexpr (MODE == 0)
                    off = (s >> 4) * 1024 + (d >> 5) * 512 +
                          ((d >> 3) & 3) * 128 + (s & 15) * 8 + (d & 7);
                else if constexpr (MODE == 1)
                    off = (s >> 4) * 1024 + (d >> 3) * 128 + (s & 15) * 8 + (d & 7);
                else
                    off = (s >> 5) * 2048 + (d >> 4) * 512 +
                          ((s >> 3) & 3) * 128 + (d & 15) * 8 + (s & 7);
                sh[wn * 8192 + off] = f2bf(v);
            }
        }
    }
    __syncthreads();
    const int bglob = bm >> 3, bml = bm & 7;
    #pragma unroll
    for (int hl = 0; hl < 2; ++hl) {
        short* dst = outb + (size_t)(bglob * 16 + bn * 2 + hl) * 65536 + bml * 8192;
        #pragma unroll
        for (int k = 0; k < 4; ++k) {
            const int e = (k * 256 + tid) * 8;
            *(bf16x8*)(dst + e) = *(const bf16x8*)(sh + hl * 8192 + e);
        }
    }
}

__global__ __launch_bounds__(256, 4) void prep_kernel(
    const float* __restrict__ query, const float* __restrict__ key,
    const float* __restrict__ value,
    const short* __restrict__ wqb, const float* __restrict__ bq,
    const short* __restrict__ wkb, const float* __restrict__ bk,
    const short* __restrict__ wvb, const float* __restrict__ bv,
    short* __restrict__ qf, short* __restrict__ kf, short* __restrict__ vf)
{
    __shared__ short sh[16384];
    const int z = blockIdx.z;
    if (z == 0)      proj_body<0>(query, wqb, bq, qf, sh);
    else if (z == 1) proj_body<1>(key,   wkb, bk, kf, sh);
    else             proj_body<2>(value, wvb, bv, vf, sh);
}

// ---------------------------------------------------------------------------
// Cooperative attention + fused O-projection.  template DEEP:
//   DEEP=1: launch_bounds(512,1) -> 256-VGPR ceiling; V in 2x8 batches,
//           batch 1 issued after QK so its latency hides under softmax.
//   DEEP=0: launch_bounds(512,2) -> the proven round-16 schedule (fallback).
// ONE barrier per head (parity-dbuf red + bf16 O slots); 1 block/CU.
// ---------------------------------------------------------------------------
template <int DEEP>
__global__ __launch_bounds__(512, (DEEP ? 1 : 2)) void attn_kernel(
    const short* Qf, const short* Kf, const short* Vf,
    const short* Wof, const float* bo, float* outp)
{
    __shared__ alignas(16) short Ohlds[32 * 1024];      // 64KB attn out, swizzled
    __shared__ alignas(16) short pbufs[8 * 32 * 40];    // 20.5KB bf16 P bounce
    __shared__ alignas(16) short oaslb[2][8][32][72];   // 72KB bf16 O slots (dbuf)
    __shared__ alignas(16) float red[2][2][16][8];      // 2KB row-sum partials

    const int tid  = threadIdx.x;
    const int lane = tid & 63;
    const int w = tid >> 6;                  // 0..7
    const int g = lane >> 4, c = lane & 15;
    const int b = blockIdx.x & 7, qt = blockIdx.x >> 3;   // XCD-friendly split

    f32x4 am[2][8] = {};  // sum over heads of normalized P (attn.mean)

    bf16x8 qfr[2][2], kA[8];
    {
        const size_t hb0 = (size_t)(b * 16) * 65536;
        #pragma unroll
        for (int at = 0; at < 2; ++at)
            #pragma unroll
            for (int kc = 0; kc < 2; ++kc)
                qfr[at][kc] = *(const bf16x8*)(Qf + hb0 +
                    (size_t)((qt * 2 + at) * 1024 + kc * 512 + g * 128 + c * 8));
        #pragma unroll
        for (int mt = 0; mt < PF; ++mt)
            kA[mt] = *(const bf16x8*)(Kf + hb0 +
                (size_t)((w * 8 + mt) * 1024 + g * 128 + c * 8));
    }

    for (int h = 0; h < 16; ++h) {
        const int par = h & 1;
        const size_t hb = (size_t)(b * 16 + h) * 65536;

        bf16x8 kB[8];
        #pragma unroll
        for (int mt = PF; mt < 8; ++mt)
            kA[mt] = *(const bf16x8*)(Kf + hb +
                (size_t)((w * 8 + mt) * 1024 + g * 128 + c * 8));
        #pragma unroll
        for (int mt = 0; mt < 8; ++mt)
            kB[mt] = *(const bf16x8*)(Kf + hb +
                (size_t)((w * 8 + mt) * 1024 + (4 + g) * 128 + c * 8));

        f32x4 p[2][8] = {};
        #pragma unroll
        for (int mt = 0; mt < 8; ++mt) {
            p[0][mt] = mfma_bf16(qfr[0][0], kA[mt], p[0][mt]);
            p[1][mt] = mfma_bf16(qfr[1][0], kA[mt], p[1][mt]);
        }
        #pragma unroll
        for (int mt = 0; mt < 8; ++mt) {
            p[0][mt] = mfma_bf16(qfr[0][1], kB[mt], p[0][mt]);
            p[1][mt] = mfma_bf16(qfr[1][1], kB[mt], p[1][mt]);
        }

        // DEEP: V batch 1 (ks=0,1) issued here -> latency hidden under softmax
        bf16x8 vfr8[8];
        if constexpr (DEEP) {
            #pragma unroll
            for (int i = 0; i < 8; ++i)
                vfr8[i] = *(const bf16x8*)(Vf + hb +
                    (size_t)(((w * 4 + (i >> 2)) * 4 + (i & 3)) * 512 +
                             g * 128 + c * 8));
        }

        // exp2 (unclamped) + per-lane partial row sums
        f32x4 rs[2] = {};
        #pragma unroll
        for (int at = 0; at < 2; ++at)
            #pragma unroll
            for (int mt = 0; mt < 8; ++mt) {
                f32x4 v = p[at][mt];
                #pragma unroll
                for (int r = 0; r < 4; ++r)
                    v[r] = __builtin_amdgcn_exp2f(v[r]);
                p[at][mt] = v;
                rs[at] += v;
            }
        #pragma unroll
        for (int off = 1; off < 16; off <<= 1)
            #pragma unroll
            for (int at = 0; at < 2; ++at)
                #pragma unroll
                for (int r = 0; r < 4; ++r)
                    rs[at][r] += __shfl_xor(rs[at][r], off);
        if (c == 0) {
            #pragma unroll
            for (int at = 0; at < 2; ++at)
                #pragma unroll
                for (int r = 0; r < 4; ++r)
                    red[par][at][g * 4 + r][w] = rs[at][r];
        }

        // PV on UNNORMALIZED P
        short* pbs = pbufs + w * 1280;
        f32x4 oa[2][4] = {};
        #pragma unroll
        for (int ks = 0; ks < 4; ++ks) {
            bf16x8 vloc[4];
            if constexpr (DEEP) {
                if (ks == 2) {      // V batch 2 (ks=2,3)
                    #pragma unroll
                    for (int i = 0; i < 8; ++i)
                        vfr8[i] = *(const bf16x8*)(Vf + hb +
                            (size_t)(((w * 4 + 2 + (i >> 2)) * 4 + (i & 3)) * 512 +
                                     g * 128 + c * 8));
                }
            } else {
                #pragma unroll
                for (int dt = 0; dt < 4; ++dt)
                    vloc[dt] = *(const bf16x8*)(Vf + hb +
                        (size_t)(((w * 4 + ks) * 4 + dt) * 512 + g * 128 + c * 8));
            }
            #pragma unroll
            for (int at = 0; at < 2; ++at)
                #pragma unroll
                for (int m2 = 0; m2 < 2; ++m2)
                    #pragma unroll
                    for (int r = 0; r < 4; ++r)
                        pbs[(at * 16 + g * 4 + r) * 40 + m2 * 16 + c] =
                            f2bf(p[at][ks * 2 + m2][r]);
            asm volatile("s_waitcnt lgkmcnt(0)" ::: "memory");
            bf16x8 pa[2];
            #pragma unroll
            for (int at = 0; at < 2; ++at)
                pa[at] = *(const bf16x8*)&pbs[(at * 16 + c) * 40 + g * 8];
            #pragma unroll
            for (int dt = 0; dt < 4; ++dt) {
                bf16x8 vv = DEEP ? vfr8[(ks & 1) * 4 + dt] : vloc[dt];
                oa[0][dt] = mfma_bf16(pa[0], vv, oa[0][dt]);
                oa[1][dt] = mfma_bf16(pa[1], vv, oa[1][dt]);
            }
        }
        // per-wave O slot (bf16, parity-buffered; plain stores, no atomics)
        #pragma unroll
        for (int at = 0; at < 2; ++at)
            #pragma unroll
            for (int dt = 0; dt < 4; ++dt)
                #pragma unroll
                for (int r = 0; r < 4; ++r)
                    oaslb[par][w][at * 16 + g * 4 + r][dt * 16 + c] =
                        f2bf(oa[at][dt][r]);

        // prefetch next head's Q frags + first PF K frags
        if (h < 15) {
            const size_t hbN = hb + 65536;
            #pragma unroll
            for (int at = 0; at < 2; ++at)
                #pragma unroll
                for (int kc = 0; kc < 2; ++kc)
                    qfr[at][kc] = *(const bf16x8*)(Qf + hbN +
                        (size_t)((qt * 2 + at) * 1024 + kc * 512 + g * 128 + c * 8));
            #pragma unroll
            for (int mt = 0; mt < PF; ++mt)
                kA[mt] = *(const bf16x8*)(Kf + hbN +
                    (size_t)((w * 8 + mt) * 1024 + g * 128 + c * 8));
        }

        __syncthreads();   // the ONE barrier per head

        // per-lane rinv + attn-mean accumulation
        #pragma unroll
        for (int at = 0; at < 2; ++at) {
            f32x4 rv;
            #pragma unroll
            for (int r = 0; r < 4; ++r) {
                f32x4 s0 = *(const f32x4*)&red[par][at][g * 4 + r][0];
                f32x4 s1 = *(const f32x4*)&red[par][at][g * 4 + r][4];
                f32x4 ss = s0 + s1;
                rv[r] = 1.0f / (ss[0] + ss[1] + ss[2] + ss[3]);
            }
            #pragma unroll
            for (int mt = 0; mt < 8; ++mt)
                am[at][mt] += p[at][mt] * rv;
        }

        // O tree-sum over 8 wave slots (bf16 unpack) + normalize -> Ohlds
        {
            const int zn = tid >> 4, zd = (tid & 15) * 4;
            const int zh = zn >> 4, zr = zn & 15;
            f32x4 s0 = *(const f32x4*)&red[par][zh][zr][0];
            f32x4 s1 = *(const f32x4*)&red[par][zh][zr][4];
            f32x4 ss = s0 + s1;
            const float inv = 1.0f / (ss[0] + ss[1] + ss[2] + ss[3]);
            f32x4 ov = {0.f, 0.f, 0.f, 0.f};
            #pragma unroll
            for (int i = 0; i < 8; ++i) {
                u32x2 uu = *(const u32x2*)&oaslb[par][i][zn][zd];
                union { unsigned u; float f; } e0, e1, e2, e3;
                e0.u = uu[0] << 16;  e1.u = uu[0] & 0xFFFF0000u;
                e2.u = uu[1] << 16;  e3.u = uu[1] & 0xFFFF0000u;
                ov[0] += e0.f; ov[1] += e1.f; ov[2] += e2.f; ov[3] += e3.f;
            }
            u32x2 pk;
            pk[0] = cvt_pk(ov[0] * inv, ov[1] * inv);
            pk[1] = cvt_pk(ov[2] * inv, ov[3] * inv);
            unsigned byt = (unsigned)(zn * 2048 + (h * 64 + zd) * 2);
            byt ^= (unsigned)((zn & 7) << 4);
            *(u32x2*)((char*)Ohlds + byt) = pk;
        }
        // no second barrier: next head's same-parity writes occur only after
        // the NEXT barrier, which every wave passes after its reads above.
    }

    __syncthreads();
    // ---- all blocks done reading qf/kf/vf hosted in d_out ----
    cg::this_grid().sync();

    // attn.mean(heads) -> out1 (clobbers qf/kf hosting)
    float* aout = outp + 8388608 + (size_t)b * 1048576;
    #pragma unroll
    for (int at = 0; at < 2; ++at)
        #pragma unroll
        for (int mt = 0; mt < 8; ++mt)
            #pragma unroll
            for (int r = 0; r < 4; ++r) {
                const int n = qt * 32 + at * 16 + g * 4 + r;
                const int m = w * 128 + mt * 16 + c;
                aout[(size_t)n * 1024 + m] = am[at][mt][r] * 0.0625f;
            }

    // tail GEMM: out[32 rows][1024] = Ohlds(32x1024) @ w_o^T + b_o.
    f32x4 acc2[2][8] = {};
    for (int kt = 0; kt < 32; ++kt) {
        bf16x8 afr[2];
        #pragma unroll
        for (int at = 0; at < 2; ++at) {
            const int row = at * 16 + c;
            unsigned byt = (unsigned)(row * 2048 + (kt * 32 + g * 8) * 2);
            byt ^= (unsigned)((row & 7) << 4);
            afr[at] = *(const bf16x8*)((const char*)Ohlds + byt);
        }
        #pragma unroll
        for (int ct = 0; ct < 8; ++ct) {
            bf16x8 bfr = *(const bf16x8*)(Wof +
                ((w * 8 + ct) * 16384 + (kt * 4 + g) * 128 + c * 8));
            acc2[0][ct] = mfma_bf16(afr[0], bfr, acc2[0][ct]);
            acc2[1][ct] = mfma_bf16(afr[1], bfr, acc2[1][ct]);
        }
    }
    #pragma unroll
    for (int ct = 0; ct < 8; ++ct) {
        const int col = w * 128 + ct * 16 + c;
        const float bv = bo[col];
        #pragma unroll
        for (int at = 0; at < 2; ++at)
            #pragma unroll
            for (int r = 0; r < 4; ++r) {
                const int n = qt * 32 + at * 16 + g * 4 + r;
                outp[(size_t)(b * 1024 + n) * 1024 + col] = acc2[at][ct][r] + bv;
            }
    }
}

extern "C" void kernel_launch(void* const* d_in, const int* in_sizes, int n_in,
                              void* d_out, int out_size, void* d_ws, size_t ws_size,
                              hipStream_t stream)
{
    (void)in_sizes; (void)n_in; (void)out_size; (void)ws_size;
    const float* query = (const float*)d_in[0];
    const float* key   = (const float*)d_in[1];
    const float* value = (const float*)d_in[2];
    const float* w_q = (const float*)d_in[3];
    const float* b_q = (const float*)d_in[4];
    const float* w_k = (const float*)d_in[5];
    const float* b_k = (const float*)d_in[6];
    const float* w_v = (const float*)d_in[7];
    const float* b_v = (const float*)d_in[8];
    const float* w_o = (const float*)d_in[9];
    const float* b_o = (const float*)d_in[10];

    float* out = (float*)d_out;              // out0 [0,8M) floats; out1 [8M,16M)
    short* vf  = (short*)d_out;              // V frags hosted in out0 low (16.78MB)
    short* wqb = (short*)(out + 4194304);    // bf16 wq (2MB)  -- out0 upper half
    short* wkb = wqb + 1048576;              // bf16 wk (1.5MB)
    short* wvb = wkb + 786432;               // bf16 wv (1.5MB)
    short* qf  = (short*)(out + 8388608);    // Q frags hosted in out1 lower half
    short* kf  = qf + 8388608;               // K frags hosted in out1 upper half
    short* wof = (short*)d_ws;               // w_o bf16 frags (2MB — only ws use)

    wconv_kernel<<<dim3(512, 4), 256, 0, stream>>>(
        w_q, w_k, w_v, w_o, wqb, wkb, wvb, wof);

    prep_kernel<<<dim3(8, 64, 3), 256, 0, stream>>>(
        query, key, value, wqb, b_q, wkb, b_k, wvb, b_v, qf, kf, vf);

    void* args[] = { (void*)&qf, (void*)&kf, (void*)&vf,
                     (void*)&wof, (void*)&b_o, (void*)&out };
    // Host-side occupancy check (graph-capture-safe, deterministic): use the
    // DEEP variant only if it can host >=1 block/CU (i.e., VGPR <= 256).
    int nb = 0;
    hipOccupancyMaxActiveBlocksPerMultiprocessor(&nb, attn_kernel<1>, 512, 0);
    if (nb >= 1)
        hipLaunchCooperativeKernel(attn_kernel<1>, dim3(256), dim3(512),
                                   args, 0u, stream);
    else
        hipLaunchCooperativeKernel(attn_kernel<0>, dim3(256), dim3(512),
                                   args, 0u, stream);
}